// Round 1
// baseline (709.958 us; speedup 1.0000x reference)
//
#include <hip/hip_runtime.h>
#include <hip/hip_bf16.h>

typedef __attribute__((ext_vector_type(8))) short bf16x8;
typedef __attribute__((ext_vector_type(4))) float f32x4;

#define EMB 128
#define NB 32

__device__ __forceinline__ unsigned short f2bf(float f) {
  unsigned u = __float_as_uint(f);
  u = u + 0x7FFFu + ((u >> 16) & 1u);   // round-to-nearest-even
  return (unsigned short)(u >> 16);
}
__device__ __forceinline__ unsigned ordf(float f) {
  unsigned u = __float_as_uint(f);
  return (u & 0x80000000u) ? ~u : (u | 0x80000000u);
}
__device__ __forceinline__ float unordf(unsigned v) {
  unsigned u = (v & 0x80000000u) ? (v & 0x7FFFFFFFu) : ~v;
  return __uint_as_float(u);
}

// ---------------- Kernel 1: neck 1x1-conv GEMM (bf16 MFMA) + CAM max/sum stats ----------------
// x: [b][K][HW] f32.  w: [EMB][K] f32.  f out: [b][HW][EMB] bf16 (raw ushort).
// Block: 256 thr = 4 waves; block covers 128 pixels x all 128 out-channels.
// Wave w owns pixels [bx*128 + w*32, +32): two 16-row m-tiles; n covers 8 o-tiles.
__global__ __launch_bounds__(256) void neck_kernel(
    const float* __restrict__ x, const float* __restrict__ w, const float* __restrict__ bias,
    unsigned short* __restrict__ f, unsigned* __restrict__ gmax, float* __restrict__ gsum,
    int K, int HW)
{
  __shared__ unsigned smax[EMB];
  __shared__ float ssum[EMB];
  const int tid = threadIdx.x;
  if (tid < EMB) { smax[tid] = 0u; ssum[tid] = 0.f; }
  __syncthreads();

  const int wv = tid >> 6, lane = tid & 63, q = lane >> 4, col = lane & 15;
  const int b = blockIdx.y;
  const int p0 = blockIdx.x * 128 + wv * 32;
  const float* __restrict__ xb = x + (size_t)b * K * HW;

  f32x4 acc[2][8];
#pragma unroll
  for (int mt = 0; mt < 2; mt++)
#pragma unroll
    for (int nt = 0; nt < 8; nt++) acc[mt][nt] = (f32x4){0.f, 0.f, 0.f, 0.f};

  const int pm0 = min(p0 + col, HW - 1);        // A-frag pixel (m-tile 0)
  const int pm1 = min(p0 + 16 + col, HW - 1);   // m-tile 1

  for (int c0 = 0; c0 < K; c0 += 32) {
    const int cb = c0 + q * 8;                  // this lane's 8 consecutive k's
    float a0[8], a1[8];
#pragma unroll
    for (int j = 0; j < 8; j++) {
      const float* row = xb + (size_t)(cb + j) * HW;
      a0[j] = row[pm0];
      a1[j] = row[pm1];
    }
    bf16x8 A0, A1;
#pragma unroll
    for (int j = 0; j < 8; j++) { A0[j] = (short)f2bf(a0[j]); A1[j] = (short)f2bf(a1[j]); }
#pragma unroll
    for (int nt = 0; nt < 8; nt++) {
      const float* wr = w + (size_t)(nt * 16 + col) * K + cb;  // B[k][n]=w[o=n][c=k], k-contig
      const float4 wa = *(const float4*)(wr);
      const float4 wb = *(const float4*)(wr + 4);
      bf16x8 Bf;
      Bf[0] = (short)f2bf(wa.x); Bf[1] = (short)f2bf(wa.y);
      Bf[2] = (short)f2bf(wa.z); Bf[3] = (short)f2bf(wa.w);
      Bf[4] = (short)f2bf(wb.x); Bf[5] = (short)f2bf(wb.y);
      Bf[6] = (short)f2bf(wb.z); Bf[7] = (short)f2bf(wb.w);
      acc[0][nt] = __builtin_amdgcn_mfma_f32_16x16x32_bf16(A0, Bf, acc[0][nt], 0, 0, 0);
      acc[1][nt] = __builtin_amdgcn_mfma_f32_16x16x32_bf16(A1, Bf, acc[1][nt], 0, 0, 0);
    }
  }

  // Epilogue: bias, bf16 store [b][p][o], and CAM max/sum partials.
#pragma unroll
  for (int nt = 0; nt < 8; nt++) {
    const int o = nt * 16 + col;
    const float bo = bias[o];
    float lmax = -3.4e38f, lsum = 0.f;
#pragma unroll
    for (int mt = 0; mt < 2; mt++) {
#pragma unroll
      for (int r = 0; r < 4; r++) {
        const int p = p0 + mt * 16 + q * 4 + r;   // D row = quad*4 + reg
        const float v = acc[mt][nt][r] + bo;
        if (p < HW) {
          f[((size_t)b * HW + p) * EMB + o] = f2bf(v);
          lmax = fmaxf(lmax, v);
          lsum += v;
        }
      }
    }
#pragma unroll
    for (int off = 16; off < 64; off <<= 1) {     // combine 4 quads (same o)
      lmax = fmaxf(lmax, __shfl_xor(lmax, off, 64));
      lsum += __shfl_xor(lsum, off, 64);
    }
    if (lane < 16) {
      atomicMax(&smax[o], ordf(lmax));
      atomicAdd(&ssum[o], lsum);
    }
  }
  __syncthreads();
  if (tid < EMB) {
    atomicMax(&gmax[b * EMB + tid], smax[tid]);
    atomicAdd(&gsum[b * EMB + tid], ssum[tid]);
  }
}

// ---------------- Kernel 2: CAM gate = sigmoid(mlp(max) + mlp(mean)) ----------------
__global__ __launch_bounds__(128) void gate_kernel(
    const unsigned* __restrict__ gmax, const float* __restrict__ gsum, float* __restrict__ gate,
    const float* __restrict__ w1a, const float* __restrict__ b1a, const float* __restrict__ w2a, const float* __restrict__ b2a,
    const float* __restrict__ w1b, const float* __restrict__ b1b, const float* __restrict__ w2b, const float* __restrict__ b2b,
    const float* __restrict__ w1c, const float* __restrict__ b1c, const float* __restrict__ w2c, const float* __restrict__ b2c)
{
  const int s = blockIdx.y, b = blockIdx.x, tid = threadIdx.x;
  const float* w1 = s == 0 ? w1a : (s == 1 ? w1b : w1c);
  const float* b1 = s == 0 ? b1a : (s == 1 ? b1b : b1c);
  const float* w2 = s == 0 ? w2a : (s == 1 ? w2b : w2c);
  const float* b2 = s == 0 ? b2a : (s == 1 ? b2b : b2c);
  const float invHW = s == 0 ? (1.f / 6400.f) : (s == 1 ? (1.f / 1600.f) : (1.f / 400.f));
  __shared__ float mx[EMB], av[EMB], hm[32], ha[32];
  const int base = (s * NB + b) * EMB;
  mx[tid] = unordf(gmax[base + tid]);
  av[tid] = gsum[base + tid] * invHW;
  __syncthreads();
  if (tid < 32) {
    float sm = b1[tid], sa = b1[tid];
    for (int c = 0; c < EMB; c++) { const float wv = w1[tid * EMB + c]; sm += wv * mx[c]; sa += wv * av[c]; }
    hm[tid] = fmaxf(sm, 0.f); ha[tid] = fmaxf(sa, 0.f);
  }
  __syncthreads();
  float v = 2.f * b2[tid];
  for (int h = 0; h < 32; h++) { const float wv = w2[tid * 32 + h]; v += wv * (hm[h] + ha[h]); }
  gate[base + tid] = 1.f / (1.f + __expf(-v));
}

// ---------------- Kernel 3: SAM smx/sav maps (channel max/mean of gate*f) ----------------
__global__ __launch_bounds__(256) void smap_kernel(
    const unsigned short* __restrict__ f0, const unsigned short* __restrict__ f1, const unsigned short* __restrict__ f2,
    const float* __restrict__ gate,
    float* __restrict__ smx0, float* __restrict__ sav0,
    float* __restrict__ smx1, float* __restrict__ sav1,
    float* __restrict__ smx2, float* __restrict__ sav2)
{
  const int lane = threadIdx.x & 63;
  const int wid = (blockIdx.x * blockDim.x + threadIdx.x) >> 6;
  const int nw = (gridDim.x * blockDim.x) >> 6;
  const int total = NB * 8400;
  for (int t = wid; t < total; t += nw) {
    const int b = t / 8400, p = t % 8400;
    const unsigned short* f; float* smx; float* sav; int s, pp, HW;
    if (p < 6400)      { s = 0; pp = p;        HW = 6400; f = f0; smx = smx0; sav = sav0; }
    else if (p < 8000) { s = 1; pp = p - 6400; HW = 1600; f = f1; smx = smx1; sav = sav1; }
    else               { s = 2; pp = p - 8000; HW = 400;  f = f2; smx = smx2; sav = sav2; }
    const unsigned u = ((const unsigned*)(f + ((size_t)b * HW + pp) * EMB))[lane];
    const float v0 = __uint_as_float(u << 16);
    const float v1 = __uint_as_float(u & 0xFFFF0000u);
    const int gb = (s * NB + b) * EMB + 2 * lane;
    const float y0 = gate[gb] * v0, y1 = gate[gb + 1] * v1;
    float m = fmaxf(y0, y1), sm = y0 + y1;
#pragma unroll
    for (int off = 1; off < 64; off <<= 1) { m = fmaxf(m, __shfl_xor(m, off, 64)); sm += __shfl_xor(sm, off, 64); }
    if (lane == 0) { smx[b * HW + pp] = m; sav[b * HW + pp] = sm * (1.f / EMB); }
  }
}

// ---------------- Kernel 4: 7x7 SAM conv at gathered pixels + final emb ----------------
__global__ __launch_bounds__(256) void gather_kernel(
    const int* __restrict__ reid_idx,
    const unsigned short* __restrict__ f0, const unsigned short* __restrict__ f1, const unsigned short* __restrict__ f2,
    const float* __restrict__ gate,
    const float* __restrict__ smx0, const float* __restrict__ sav0,
    const float* __restrict__ smx1, const float* __restrict__ sav1,
    const float* __restrict__ smx2, const float* __restrict__ sav2,
    const float* __restrict__ sw0, const float* __restrict__ sw1, const float* __restrict__ sw2,
    float* __restrict__ emb)
{
  const int lane = threadIdx.x & 63;
  const int wid = (blockIdx.x * blockDim.x + threadIdx.x) >> 6;
  if (wid >= NB * 100) return;
  const int b = wid / 100, k = wid % 100;
  const int idx = reid_idx[b * 100 + k];
  const unsigned short* f; const float* smx; const float* sav; const float* sw;
  int s, pp, W, H, HW;
  if (idx < 6400)      { s = 0; pp = idx;        W = 80; H = 80; HW = 6400; f = f0; smx = smx0; sav = sav0; sw = sw0; }
  else if (idx < 8000) { s = 1; pp = idx - 6400; W = 40; H = 40; HW = 1600; f = f1; smx = smx1; sav = sav1; sw = sw1; }
  else                 { s = 2; pp = idx - 8000; W = 20; H = 20; HW = 400;  f = f2; smx = smx2; sav = sav2; sw = sw2; }
  const int y = pp / W, xx0 = pp % W;
  float c = 0.f;
  if (lane < 49) {
    const int dy = lane / 7 - 3, dx = lane % 7 - 3;
    const int yy = y + dy, xx = xx0 + dx;
    if (yy >= 0 && yy < H && xx >= 0 && xx < W) {
      const int qq = b * HW + yy * W + xx;
      c = smx[qq] * sw[lane] + sav[qq] * sw[49 + lane];  // channel0=smx, channel1=sav
    }
  }
#pragma unroll
  for (int off = 1; off < 64; off <<= 1) c += __shfl_xor(c, off, 64);
  const float sig = 1.f / (1.f + __expf(-c));
  const unsigned u = ((const unsigned*)(f + ((size_t)b * HW + pp) * EMB))[lane];
  const float v0 = __uint_as_float(u << 16);
  const float v1 = __uint_as_float(u & 0xFFFF0000u);
  const int gb = (s * NB + b) * EMB + 2 * lane;
  const float o0 = v0 * (1.f + sig * gate[gb]);
  const float o1 = v1 * (1.f + sig * gate[gb + 1]);
  *(float2*)(emb + ((size_t)(b * 100 + k)) * EMB + 2 * lane) = make_float2(o0, o1);
}

extern "C" void kernel_launch(void* const* d_in, const int* in_sizes, int n_in,
                              void* d_out, int out_size, void* d_ws, size_t ws_size,
                              hipStream_t stream)
{
  const float* xin0 = (const float*)d_in[0];
  const float* xin1 = (const float*)d_in[1];
  const float* xin2 = (const float*)d_in[2];
  const float* yolo = (const float*)d_in[3];
  const int*   reid = (const int*)d_in[4];
  const float* nw0 = (const float*)d_in[5];  const float* nb0 = (const float*)d_in[6];
  const float* nw1 = (const float*)d_in[7];  const float* nb1 = (const float*)d_in[8];
  const float* nw2 = (const float*)d_in[9];  const float* nb2 = (const float*)d_in[10];
  const float* c0w1 = (const float*)d_in[11]; const float* c0b1 = (const float*)d_in[12];
  const float* c0w2 = (const float*)d_in[13]; const float* c0b2 = (const float*)d_in[14];
  const float* c0sw = (const float*)d_in[15];
  const float* c1w1 = (const float*)d_in[16]; const float* c1b1 = (const float*)d_in[17];
  const float* c1w2 = (const float*)d_in[18]; const float* c1b2 = (const float*)d_in[19];
  const float* c1sw = (const float*)d_in[20];
  const float* c2w1 = (const float*)d_in[21]; const float* c2b1 = (const float*)d_in[22];
  const float* c2w2 = (const float*)d_in[23]; const float* c2b2 = (const float*)d_in[24];
  const float* c2sw = (const float*)d_in[25];

  char* ws = (char*)d_ws;
  size_t off = 0;
  auto alloc = [&](size_t bytes) -> void* {
    void* p = ws + off; off += (bytes + 255) & ~(size_t)255; return p;
  };
  unsigned short* f0 = (unsigned short*)alloc((size_t)NB * 6400 * EMB * 2);
  unsigned short* f1 = (unsigned short*)alloc((size_t)NB * 1600 * EMB * 2);
  unsigned short* f2 = (unsigned short*)alloc((size_t)NB * 400 * EMB * 2);
  unsigned* gmax = (unsigned*)alloc(3 * NB * EMB * 4);   // contiguous with gsum (sizes are 256-aligned)
  float* gsum = (float*)alloc(3 * NB * EMB * 4);
  float* gate = (float*)alloc(3 * NB * EMB * 4);
  float* smx0 = (float*)alloc((size_t)NB * 6400 * 4);
  float* sav0 = (float*)alloc((size_t)NB * 6400 * 4);
  float* smx1 = (float*)alloc((size_t)NB * 1600 * 4);
  float* sav1 = (float*)alloc((size_t)NB * 1600 * 4);
  float* smx2 = (float*)alloc((size_t)NB * 400 * 4);
  float* sav2 = (float*)alloc((size_t)NB * 400 * 4);

  // zero the atomic stats (gmax+gsum are contiguous)
  hipMemsetAsync(gmax, 0, (size_t)2 * 3 * NB * EMB * 4, stream);
  // yolo passthrough
  hipMemcpyAsync(d_out, yolo, (size_t)NB * 8400 * 6 * 4, hipMemcpyDeviceToDevice, stream);

  dim3 blk(256);
  neck_kernel<<<dim3(50, NB), blk, 0, stream>>>(xin0, nw0, nb0, f0, gmax + 0 * NB * EMB, gsum + 0 * NB * EMB, 256, 6400);
  neck_kernel<<<dim3(13, NB), blk, 0, stream>>>(xin1, nw1, nb1, f1, gmax + 1 * NB * EMB, gsum + 1 * NB * EMB, 512, 1600);
  neck_kernel<<<dim3(4,  NB), blk, 0, stream>>>(xin2, nw2, nb2, f2, gmax + 2 * NB * EMB, gsum + 2 * NB * EMB, 1024, 400);

  gate_kernel<<<dim3(NB, 3), dim3(128), 0, stream>>>(gmax, gsum, gate,
      c0w1, c0b1, c0w2, c0b2, c1w1, c1b1, c1w2, c1b2, c2w1, c2b1, c2w2, c2b2);

  smap_kernel<<<dim3(4200), blk, 0, stream>>>(f0, f1, f2, gate, smx0, sav0, smx1, sav1, smx2, sav2);

  gather_kernel<<<dim3(800), blk, 0, stream>>>(reid, f0, f1, f2, gate,
      smx0, sav0, smx1, sav1, smx2, sav2, c0sw, c1sw, c2sw,
      (float*)d_out + (size_t)NB * 8400 * 6);
}

// Round 2
// 581.086 us; speedup vs baseline: 1.2218x; 1.2218x over previous
//
#include <hip/hip_runtime.h>
#include <hip/hip_bf16.h>

typedef __attribute__((ext_vector_type(8))) short bf16x8;
typedef __attribute__((ext_vector_type(4))) float f32x4;

#define EMB 128
#define NB 32

__device__ __forceinline__ unsigned short f2bf(float f) {
  unsigned u = __float_as_uint(f);
  u = u + 0x7FFFu + ((u >> 16) & 1u);   // round-to-nearest-even
  return (unsigned short)(u >> 16);
}
__device__ __forceinline__ unsigned ordf(float f) {
  unsigned u = __float_as_uint(f);
  return (u & 0x80000000u) ? ~u : (u | 0x80000000u);
}
__device__ __forceinline__ float unordf(unsigned v) {
  unsigned u = (v & 0x80000000u) ? (v & 0x7FFFFFFFu) : ~v;
  return __uint_as_float(u);
}
__device__ __forceinline__ void gl_lds16(const float* g, float* l) {
  __builtin_amdgcn_global_load_lds(
      (const __attribute__((address_space(1))) void*)g,
      (__attribute__((address_space(3))) void*)l, 16, 0, 0);
}

// ---------------- Kernel 0: weights f32 -> bf16 (once, tiny) ----------------
__global__ __launch_bounds__(256) void wconv_kernel(
    const float* __restrict__ w0, const float* __restrict__ w1, const float* __restrict__ w2,
    unsigned short* __restrict__ o0, unsigned short* __restrict__ o1, unsigned short* __restrict__ o2)
{
  const int t = blockIdx.x * 256 + threadIdx.x;  // grid covers 229376 exactly
  const float* w; unsigned short* o; int i;
  if (t < 32768)       { w = w0; o = o0; i = t; }
  else if (t < 98304)  { w = w1; o = o1; i = t - 32768; }
  else                 { w = w2; o = o2; i = t - 98304; }
  o[i] = f2bf(w[i]);
}

// ---------------- Kernel 1: merged neck GEMM (all 3 scales) + CAM stats ----------------
// x: [b][K][HW] f32.  wb: [EMB][K] bf16.  f out: [b][HW][EMB] bf16.
// Block: 256 thr = 4 waves; tile = 128 pixels x 128 out-channels; BK=64 staged in LDS.
// Blocks 0..127: scale2 (K=1024, deepest first), 128..543: scale1, 544..2143: scale0.
__global__ __launch_bounds__(256, 3) void neck_kernel(
    const float* __restrict__ x0, const float* __restrict__ x1, const float* __restrict__ x2,
    const unsigned short* __restrict__ wb0, const unsigned short* __restrict__ wb1, const unsigned short* __restrict__ wb2,
    const float* __restrict__ bias0, const float* __restrict__ bias1, const float* __restrict__ bias2,
    unsigned short* __restrict__ f0o, unsigned short* __restrict__ f1o, unsigned short* __restrict__ f2o,
    unsigned* __restrict__ gmax, float* __restrict__ gsum)
{
  __shared__ float xs[64 * 128];
  __shared__ unsigned smax[EMB];
  __shared__ float ssum[EMB];
  const int tid = threadIdx.x;
  if (tid < EMB) { smax[tid] = 0u; ssum[tid] = 0.f; }   // K-loop barriers order this vs epilogue

  const int bid = blockIdx.x;
  int sidx, r, K, HW;
  const float* x; const unsigned short* wb; const float* bias; unsigned short* f;
  if (bid < 128)      { sidx = 2; r = bid;       x = x2; wb = wb2; bias = bias2; f = f2o; K = 1024; HW = 400;  }
  else if (bid < 544) { sidx = 1; r = bid - 128; x = x1; wb = wb1; bias = bias1; f = f1o; K = 512;  HW = 1600; }
  else                { sidx = 0; r = bid - 544; x = x0; wb = wb0; bias = bias0; f = f0o; K = 256;  HW = 6400; }
  const int tile = r / NB, b = r % NB;
  const int p0 = tile * 128;
  const int wv = tid >> 6, lane = tid & 63, q = lane >> 4, col = lane & 15;
  const float* __restrict__ xb = x + (size_t)b * K * HW;
  const int pw = p0 + wv * 32;                       // this wave's 32-pixel window

  f32x4 acc[2][8];
#pragma unroll
  for (int mt = 0; mt < 2; mt++)
#pragma unroll
    for (int nt = 0; nt < 8; nt++) acc[mt][nt] = (f32x4){0.f, 0.f, 0.f, 0.f};

  const int pofs = min(p0 + (lane & 31) * 4, HW - 4);  // clamped (garbage masked later)
  const int lrow = lane >> 5;

  for (int k0 = 0; k0 < K; k0 += 64) {
    // stage 64 rows x 128 px f32 -> LDS; wave wv owns rows [wv*16, wv*16+16)
    const float* gp0 = xb + (size_t)(k0 + wv * 16 + lrow) * HW + pofs;
    float* lp0 = &xs[(wv * 16) * 128];
#pragma unroll
    for (int i = 0; i < 8; i++)
      gl_lds16(gp0 + (size_t)(2 * i) * HW, lp0 + (2 * i) * 128);
    __syncthreads();

#pragma unroll
    for (int kk = 0; kk < 2; kk++) {
      const int rb = kk * 32 + q * 8;                // this lane's 8 consecutive k's (LDS row)
      float av0[8], av1[8];
#pragma unroll
      for (int j = 0; j < 8; j++) {
        av0[j] = xs[(rb + j) * 128 + (wv * 32) + col];
        av1[j] = xs[(rb + j) * 128 + (wv * 32) + 16 + col];
      }
      bf16x8 A0, A1;
#pragma unroll
      for (int j = 0; j < 8; j++) { A0[j] = (short)f2bf(av0[j]); A1[j] = (short)f2bf(av1[j]); }
      const int cg = k0 + rb;
#pragma unroll
      for (int nt = 0; nt < 8; nt++) {
        const bf16x8 B = *(const bf16x8*)(wb + (size_t)(nt * 16 + col) * K + cg);  // 16B aligned
        acc[0][nt] = __builtin_amdgcn_mfma_f32_16x16x32_bf16(A0, B, acc[0][nt], 0, 0, 0);
        acc[1][nt] = __builtin_amdgcn_mfma_f32_16x16x32_bf16(A1, B, acc[1][nt], 0, 0, 0);
      }
    }
    __syncthreads();
  }

  // Epilogue: bias, bf16 store [b][p][o], CAM max/sum partials.
#pragma unroll
  for (int nt = 0; nt < 8; nt++) {
    const int o = nt * 16 + col;
    const float bo = bias[o];
    float lmax = -3.4e38f, lsum = 0.f;
#pragma unroll
    for (int mt = 0; mt < 2; mt++) {
#pragma unroll
      for (int rr = 0; rr < 4; rr++) {
        const int p = pw + mt * 16 + q * 4 + rr;     // D row = quad*4 + reg
        const float v = acc[mt][nt][rr] + bo;
        if (p < HW) {
          f[((size_t)b * HW + p) * EMB + o] = f2bf(v);
          lmax = fmaxf(lmax, v);
          lsum += v;
        }
      }
    }
#pragma unroll
    for (int off = 16; off < 64; off <<= 1) {        // combine 4 quads (same o)
      lmax = fmaxf(lmax, __shfl_xor(lmax, off, 64));
      lsum += __shfl_xor(lsum, off, 64);
    }
    if (lane < 16) {
      atomicMax(&smax[o], ordf(lmax));
      atomicAdd(&ssum[o], lsum);
    }
  }
  __syncthreads();
  if (tid < EMB) {
    atomicMax(&gmax[(sidx * NB + b) * EMB + tid], smax[tid]);
    atomicAdd(&gsum[(sidx * NB + b) * EMB + tid], ssum[tid]);
  }
}

// ---------------- Kernel 2: CAM gate = sigmoid(mlp(max) + mlp(mean)) ----------------
__global__ __launch_bounds__(128) void gate_kernel(
    const unsigned* __restrict__ gmax, const float* __restrict__ gsum, float* __restrict__ gate,
    const float* __restrict__ w1a, const float* __restrict__ b1a, const float* __restrict__ w2a, const float* __restrict__ b2a,
    const float* __restrict__ w1b, const float* __restrict__ b1b, const float* __restrict__ w2b, const float* __restrict__ b2b,
    const float* __restrict__ w1c, const float* __restrict__ b1c, const float* __restrict__ w2c, const float* __restrict__ b2c)
{
  const int s = blockIdx.y, b = blockIdx.x, tid = threadIdx.x;
  const float* w1 = s == 0 ? w1a : (s == 1 ? w1b : w1c);
  const float* b1 = s == 0 ? b1a : (s == 1 ? b1b : b1c);
  const float* w2 = s == 0 ? w2a : (s == 1 ? w2b : w2c);
  const float* b2 = s == 0 ? b2a : (s == 1 ? b2b : b2c);
  const float invHW = s == 0 ? (1.f / 6400.f) : (s == 1 ? (1.f / 1600.f) : (1.f / 400.f));
  __shared__ float mx[EMB], av[EMB], hm[32], ha[32];
  const int base = (s * NB + b) * EMB;
  mx[tid] = unordf(gmax[base + tid]);
  av[tid] = gsum[base + tid] * invHW;
  __syncthreads();
  if (tid < 32) {
    float sm = b1[tid], sa = b1[tid];
    for (int c = 0; c < EMB; c++) { const float wv = w1[tid * EMB + c]; sm += wv * mx[c]; sa += wv * av[c]; }
    hm[tid] = fmaxf(sm, 0.f); ha[tid] = fmaxf(sa, 0.f);
  }
  __syncthreads();
  float v = 2.f * b2[tid];
  for (int h = 0; h < 32; h++) { const float wv = w2[tid * 32 + h]; v += wv * (hm[h] + ha[h]); }
  gate[base + tid] = 1.f / (1.f + __expf(-v));
}

// ---------------- Kernel 3: SAM smx/sav maps (channel max/mean of gate*f) ----------------
__global__ __launch_bounds__(256) void smap_kernel(
    const unsigned short* __restrict__ f0, const unsigned short* __restrict__ f1, const unsigned short* __restrict__ f2,
    const float* __restrict__ gate,
    float* __restrict__ smx0, float* __restrict__ sav0,
    float* __restrict__ smx1, float* __restrict__ sav1,
    float* __restrict__ smx2, float* __restrict__ sav2)
{
  const int lane = threadIdx.x & 63;
  const int wid = (blockIdx.x * blockDim.x + threadIdx.x) >> 6;
  const int nw = (gridDim.x * blockDim.x) >> 6;
  const int total = NB * 8400;
  for (int t = wid; t < total; t += nw) {
    const int b = t / 8400, p = t % 8400;
    const unsigned short* f; float* smx; float* sav; int s, pp, HW;
    if (p < 6400)      { s = 0; pp = p;        HW = 6400; f = f0; smx = smx0; sav = sav0; }
    else if (p < 8000) { s = 1; pp = p - 6400; HW = 1600; f = f1; smx = smx1; sav = sav1; }
    else               { s = 2; pp = p - 8000; HW = 400;  f = f2; smx = smx2; sav = sav2; }
    const unsigned u = ((const unsigned*)(f + ((size_t)b * HW + pp) * EMB))[lane];
    const float v0 = __uint_as_float(u << 16);
    const float v1 = __uint_as_float(u & 0xFFFF0000u);
    const int gb = (s * NB + b) * EMB + 2 * lane;
    const float y0 = gate[gb] * v0, y1 = gate[gb + 1] * v1;
    float m = fmaxf(y0, y1), sm = y0 + y1;
#pragma unroll
    for (int off = 1; off < 64; off <<= 1) { m = fmaxf(m, __shfl_xor(m, off, 64)); sm += __shfl_xor(sm, off, 64); }
    if (lane == 0) { smx[b * HW + pp] = m; sav[b * HW + pp] = sm * (1.f / EMB); }
  }
}

// ---------------- Kernel 4: 7x7 SAM conv at gathered pixels + final emb ----------------
__global__ __launch_bounds__(256) void gather_kernel(
    const int* __restrict__ reid_idx,
    const unsigned short* __restrict__ f0, const unsigned short* __restrict__ f1, const unsigned short* __restrict__ f2,
    const float* __restrict__ gate,
    const float* __restrict__ smx0, const float* __restrict__ sav0,
    const float* __restrict__ smx1, const float* __restrict__ sav1,
    const float* __restrict__ smx2, const float* __restrict__ sav2,
    const float* __restrict__ sw0, const float* __restrict__ sw1, const float* __restrict__ sw2,
    float* __restrict__ emb)
{
  const int lane = threadIdx.x & 63;
  const int wid = (blockIdx.x * blockDim.x + threadIdx.x) >> 6;
  if (wid >= NB * 100) return;
  const int b = wid / 100, k = wid % 100;
  const int idx = reid_idx[b * 100 + k];
  const unsigned short* f; const float* smx; const float* sav; const float* sw;
  int s, pp, W, H, HW;
  if (idx < 6400)      { s = 0; pp = idx;        W = 80; H = 80; HW = 6400; f = f0; smx = smx0; sav = sav0; sw = sw0; }
  else if (idx < 8000) { s = 1; pp = idx - 6400; W = 40; H = 40; HW = 1600; f = f1; smx = smx1; sav = sav1; sw = sw1; }
  else                 { s = 2; pp = idx - 8000; W = 20; H = 20; HW = 400;  f = f2; smx = smx2; sav = sav2; sw = sw2; }
  const int y = pp / W, xx0 = pp % W;
  float c = 0.f;
  if (lane < 49) {
    const int dy = lane / 7 - 3, dx = lane % 7 - 3;
    const int yy = y + dy, xx = xx0 + dx;
    if (yy >= 0 && yy < H && xx >= 0 && xx < W) {
      const int qq = b * HW + yy * W + xx;
      c = smx[qq] * sw[lane] + sav[qq] * sw[49 + lane];  // channel0=smx, channel1=sav
    }
  }
#pragma unroll
  for (int off = 1; off < 64; off <<= 1) c += __shfl_xor(c, off, 64);
  const float sig = 1.f / (1.f + __expf(-c));
  const unsigned u = ((const unsigned*)(f + ((size_t)b * HW + pp) * EMB))[lane];
  const float v0 = __uint_as_float(u << 16);
  const float v1 = __uint_as_float(u & 0xFFFF0000u);
  const int gb = (s * NB + b) * EMB + 2 * lane;
  const float o0 = v0 * (1.f + sig * gate[gb]);
  const float o1 = v1 * (1.f + sig * gate[gb + 1]);
  *(float2*)(emb + ((size_t)(b * 100 + k)) * EMB + 2 * lane) = make_float2(o0, o1);
}

extern "C" void kernel_launch(void* const* d_in, const int* in_sizes, int n_in,
                              void* d_out, int out_size, void* d_ws, size_t ws_size,
                              hipStream_t stream)
{
  const float* xin0 = (const float*)d_in[0];
  const float* xin1 = (const float*)d_in[1];
  const float* xin2 = (const float*)d_in[2];
  const float* yolo = (const float*)d_in[3];
  const int*   reid = (const int*)d_in[4];
  const float* nw0 = (const float*)d_in[5];  const float* nb0 = (const float*)d_in[6];
  const float* nw1 = (const float*)d_in[7];  const float* nb1 = (const float*)d_in[8];
  const float* nw2 = (const float*)d_in[9];  const float* nb2 = (const float*)d_in[10];
  const float* c0w1 = (const float*)d_in[11]; const float* c0b1 = (const float*)d_in[12];
  const float* c0w2 = (const float*)d_in[13]; const float* c0b2 = (const float*)d_in[14];
  const float* c0sw = (const float*)d_in[15];
  const float* c1w1 = (const float*)d_in[16]; const float* c1b1 = (const float*)d_in[17];
  const float* c1w2 = (const float*)d_in[18]; const float* c1b2 = (const float*)d_in[19];
  const float* c1sw = (const float*)d_in[20];
  const float* c2w1 = (const float*)d_in[21]; const float* c2b1 = (const float*)d_in[22];
  const float* c2w2 = (const float*)d_in[23]; const float* c2b2 = (const float*)d_in[24];
  const float* c2sw = (const float*)d_in[25];

  char* ws = (char*)d_ws;
  size_t off = 0;
  auto alloc = [&](size_t bytes) -> void* {
    void* p = ws + off; off += (bytes + 255) & ~(size_t)255; return p;
  };
  unsigned short* f0 = (unsigned short*)alloc((size_t)NB * 6400 * EMB * 2);
  unsigned short* f1 = (unsigned short*)alloc((size_t)NB * 1600 * EMB * 2);
  unsigned short* f2 = (unsigned short*)alloc((size_t)NB * 400 * EMB * 2);
  unsigned* gmax = (unsigned*)alloc(3 * NB * EMB * 4);   // contiguous with gsum
  float* gsum = (float*)alloc(3 * NB * EMB * 4);
  float* gate = (float*)alloc(3 * NB * EMB * 4);
  float* smx0 = (float*)alloc((size_t)NB * 6400 * 4);
  float* sav0 = (float*)alloc((size_t)NB * 6400 * 4);
  float* smx1 = (float*)alloc((size_t)NB * 1600 * 4);
  float* sav1 = (float*)alloc((size_t)NB * 1600 * 4);
  float* smx2 = (float*)alloc((size_t)NB * 400 * 4);
  float* sav2 = (float*)alloc((size_t)NB * 400 * 4);
  unsigned short* wb0 = (unsigned short*)alloc(32768 * 2);
  unsigned short* wb1 = (unsigned short*)alloc(65536 * 2);
  unsigned short* wb2 = (unsigned short*)alloc(131072 * 2);

  hipMemsetAsync(gmax, 0, (size_t)2 * 3 * NB * EMB * 4, stream);
  hipMemcpyAsync(d_out, yolo, (size_t)NB * 8400 * 6 * 4, hipMemcpyDeviceToDevice, stream);

  wconv_kernel<<<dim3(896), dim3(256), 0, stream>>>(nw0, nw1, nw2, wb0, wb1, wb2);

  neck_kernel<<<dim3(2144), dim3(256), 0, stream>>>(
      xin0, xin1, xin2, wb0, wb1, wb2, nb0, nb1, nb2, f0, f1, f2, gmax, gsum);

  gate_kernel<<<dim3(NB, 3), dim3(128), 0, stream>>>(gmax, gsum, gate,
      c0w1, c0b1, c0w2, c0b2, c1w1, c1b1, c1w2, c1b2, c2w1, c2b1, c2w2, c2b2);

  smap_kernel<<<dim3(4200), dim3(256), 0, stream>>>(f0, f1, f2, gate, smx0, sav0, smx1, sav1, smx2, sav2);

  gather_kernel<<<dim3(800), dim3(256), 0, stream>>>(reid, f0, f1, f2, gate,
      smx0, sav0, smx1, sav1, smx2, sav2, c0sw, c1sw, c2sw,
      (float*)d_out + (size_t)NB * 8400 * 6);
}

// Round 3
// 572.691 us; speedup vs baseline: 1.2397x; 1.0147x over previous
//
#include <hip/hip_runtime.h>
#include <hip/hip_bf16.h>

typedef __attribute__((ext_vector_type(8))) short bf16x8;
typedef __attribute__((ext_vector_type(4))) float f32x4;

#define EMB 128
#define NB 32

__device__ __forceinline__ short f2bf(float f) {
  __bf16 h = (__bf16)f;                       // gfx950: v_cvt bf16, RNE
  return __builtin_bit_cast(short, h);
}
__device__ __forceinline__ unsigned ordf(float f) {
  unsigned u = __float_as_uint(f);
  return (u & 0x80000000u) ? ~u : (u | 0x80000000u);
}
__device__ __forceinline__ float unordf(unsigned v) {
  unsigned u = (v & 0x80000000u) ? (v & 0x7FFFFFFFu) : ~v;
  return __uint_as_float(u);
}
__device__ __forceinline__ void gl_lds16(const float* g, float* l) {
  __builtin_amdgcn_global_load_lds(
      (const __attribute__((address_space(1))) void*)g,
      (__attribute__((address_space(3))) void*)l, 16, 0, 0);
}

// ---------------- Kernel 0: weights f32 -> bf16 + zero stats ----------------
__global__ __launch_bounds__(256) void wconv_kernel(
    const float* __restrict__ w0, const float* __restrict__ w1, const float* __restrict__ w2,
    unsigned short* __restrict__ o0, unsigned short* __restrict__ o1, unsigned short* __restrict__ o2,
    unsigned* __restrict__ stats)   // gmax||gsum contiguous, 24576 words
{
  const int t = blockIdx.x * 256 + threadIdx.x;  // grid covers 229376 exactly
  if (t < 24576) stats[t] = 0u;
  const float* w; unsigned short* o; int i;
  if (t < 32768)       { w = w0; o = o0; i = t; }
  else if (t < 98304)  { w = w1; o = o1; i = t - 32768; }
  else                 { w = w2; o = o2; i = t - 98304; }
  o[i] = (unsigned short)f2bf(w[i]);
}

// ---------------- Kernel 1: merged neck GEMM, barrier-free per-wave pipeline ----------------
// x: [b][K][HW] f32.  wb: [EMB][K] bf16.  f out: [b][HW][EMB] bf16.
// Block: 4 waves; each wave owns 32 pixels x 128 out-channels, stages its own
// 32px x 32k slice into private LDS (ping-pong), NO barriers in the K-loop.
__global__ __launch_bounds__(256, 4) void neck_kernel(
    const float* __restrict__ x0, const float* __restrict__ x1, const float* __restrict__ x2,
    const unsigned short* __restrict__ wb0, const unsigned short* __restrict__ wb1, const unsigned short* __restrict__ wb2,
    const float* __restrict__ bias0, const float* __restrict__ bias1, const float* __restrict__ bias2,
    unsigned short* __restrict__ f0o, unsigned short* __restrict__ f1o, unsigned short* __restrict__ f2o,
    unsigned* __restrict__ gmax, float* __restrict__ gsum)
{
  __shared__ float xs[4][2][32 * 32];   // [wave][pingpong][k-row][px]
  __shared__ unsigned smax[EMB];
  __shared__ float ssum[EMB];
  const int tid = threadIdx.x;
  if (tid < EMB) { smax[tid] = 0u; ssum[tid] = 0.f; }
  __syncthreads();                      // init visible before any wave's epilogue

  const int bid = blockIdx.x;
  int sidx, r, K, HW;
  const float* x; const unsigned short* wb; const float* bias; unsigned short* f;
  if (bid < 128)      { sidx = 2; r = bid;       x = x2; wb = wb2; bias = bias2; f = f2o; K = 1024; HW = 400;  }
  else if (bid < 544) { sidx = 1; r = bid - 128; x = x1; wb = wb1; bias = bias1; f = f1o; K = 512;  HW = 1600; }
  else                { sidx = 0; r = bid - 544; x = x0; wb = wb0; bias = bias0; f = f0o; K = 256;  HW = 6400; }
  const int tile = r / NB, b = r % NB;
  const int wv = tid >> 6, lane = tid & 63, q = lane >> 4, col = lane & 15;
  const int pw = tile * 128 + wv * 32;           // this wave's 32-pixel window
  const float* __restrict__ xb = x + (size_t)b * K * HW;

  // staging: one gl_lds16 instr = 8 rows x 128B; lane L -> row L/8, px-granule L%8
  const int sg_row = lane >> 3;
  const int sg_off = min(pw + (lane & 7) * 4, HW - 4);   // clamped; garbage masked at epilogue
  float* buf0 = xs[wv][0];
  float* buf1 = xs[wv][1];

  f32x4 acc[2][8];
#pragma unroll
  for (int mt = 0; mt < 2; mt++)
#pragma unroll
    for (int nt = 0; nt < 8; nt++) acc[mt][nt] = (f32x4){0.f, 0.f, 0.f, 0.f};

#define STAGE(kb, l) do {                                             \
    const float* _g = xb + (size_t)((kb) + sg_row) * HW + sg_off;     \
    _Pragma("unroll")                                                 \
    for (int _i = 0; _i < 4; _i++)                                    \
      gl_lds16(_g + (size_t)(8 * _i) * HW, (l) + _i * 256);           \
  } while (0)

#define COMPUTE(kg, l) do {                                           \
    float av0[8], av1[8];                                             \
    _Pragma("unroll")                                                 \
    for (int _j = 0; _j < 8; _j++) {                                  \
      av0[_j] = (l)[(q * 8 + _j) * 32 + col];                         \
      av1[_j] = (l)[(q * 8 + _j) * 32 + col + 16];                    \
    }                                                                 \
    bf16x8 A0, A1;                                                    \
    _Pragma("unroll")                                                 \
    for (int _j = 0; _j < 8; _j++) { A0[_j] = f2bf(av0[_j]); A1[_j] = f2bf(av1[_j]); } \
    _Pragma("unroll")                                                 \
    for (int _nt = 0; _nt < 8; _nt++) {                               \
      const bf16x8 B = *(const bf16x8*)(wb + (size_t)(_nt * 16 + col) * K + (kg) + q * 8); \
      acc[0][_nt] = __builtin_amdgcn_mfma_f32_16x16x32_bf16(A0, B, acc[0][_nt], 0, 0, 0); \
      acc[1][_nt] = __builtin_amdgcn_mfma_f32_16x16x32_bf16(A1, B, acc[1][_nt], 0, 0, 0); \
    }                                                                 \
  } while (0)

  STAGE(0, buf0);
  for (int k0 = 0; k0 < K; k0 += 64) {
    STAGE(k0 + 32, buf1);
    COMPUTE(k0, buf0);
    if (k0 + 64 < K) STAGE(k0 + 64, buf0);
    COMPUTE(k0 + 32, buf1);
  }
#undef STAGE
#undef COMPUTE

  // Epilogue: bias, bf16 store [b][p][o], CAM max/sum partials.
#pragma unroll
  for (int nt = 0; nt < 8; nt++) {
    const int o = nt * 16 + col;
    const float bo = bias[o];
    float lmax = -3.4e38f, lsum = 0.f;
#pragma unroll
    for (int mt = 0; mt < 2; mt++) {
#pragma unroll
      for (int rr = 0; rr < 4; rr++) {
        const int p = pw + mt * 16 + q * 4 + rr;     // D row = quad*4 + reg
        const float v = acc[mt][nt][rr] + bo;
        if (p < HW) {
          f[((size_t)b * HW + p) * EMB + o] = (unsigned short)f2bf(v);
          lmax = fmaxf(lmax, v);
          lsum += v;
        }
      }
    }
#pragma unroll
    for (int off = 16; off < 64; off <<= 1) {        // combine 4 quads (same o)
      lmax = fmaxf(lmax, __shfl_xor(lmax, off, 64));
      lsum += __shfl_xor(lsum, off, 64);
    }
    if (lane < 16) {
      atomicMax(&smax[o], ordf(lmax));
      atomicAdd(&ssum[o], lsum);
    }
  }
  __syncthreads();
  if (tid < EMB) {
    atomicMax(&gmax[(sidx * NB + b) * EMB + tid], smax[tid]);
    atomicAdd(&gsum[(sidx * NB + b) * EMB + tid], ssum[tid]);
  }
}

// ---------------- Kernel 2: CAM gate = sigmoid(mlp(max) + mlp(mean)) ----------------
__global__ __launch_bounds__(128) void gate_kernel(
    const unsigned* __restrict__ gmax, const float* __restrict__ gsum, float* __restrict__ gate,
    const float* __restrict__ w1a, const float* __restrict__ b1a, const float* __restrict__ w2a, const float* __restrict__ b2a,
    const float* __restrict__ w1b, const float* __restrict__ b1b, const float* __restrict__ w2b, const float* __restrict__ b2b,
    const float* __restrict__ w1c, const float* __restrict__ b1c, const float* __restrict__ w2c, const float* __restrict__ b2c)
{
  const int s = blockIdx.y, b = blockIdx.x, tid = threadIdx.x;
  const float* w1 = s == 0 ? w1a : (s == 1 ? w1b : w1c);
  const float* b1 = s == 0 ? b1a : (s == 1 ? b1b : b1c);
  const float* w2 = s == 0 ? w2a : (s == 1 ? w2b : w2c);
  const float* b2 = s == 0 ? b2a : (s == 1 ? b2b : b2c);
  const float invHW = s == 0 ? (1.f / 6400.f) : (s == 1 ? (1.f / 1600.f) : (1.f / 400.f));
  __shared__ float mx[EMB], av[EMB], hm[32], ha[32];
  const int base = (s * NB + b) * EMB;
  mx[tid] = unordf(gmax[base + tid]);
  av[tid] = gsum[base + tid] * invHW;
  __syncthreads();
  if (tid < 32) {
    float sm = b1[tid], sa = b1[tid];
    for (int c = 0; c < EMB; c++) { const float wv = w1[tid * EMB + c]; sm += wv * mx[c]; sa += wv * av[c]; }
    hm[tid] = fmaxf(sm, 0.f); ha[tid] = fmaxf(sa, 0.f);
  }
  __syncthreads();
  float v = 2.f * b2[tid];
  for (int h = 0; h < 32; h++) { const float wv = w2[tid * 32 + h]; v += wv * (hm[h] + ha[h]); }
  gate[base + tid] = 1.f / (1.f + __expf(-v));
}

// ---------------- Kernel 3: SAM smx/sav maps (channel max/mean of gate*f) ----------------
__global__ __launch_bounds__(256) void smap_kernel(
    const unsigned short* __restrict__ f0, const unsigned short* __restrict__ f1, const unsigned short* __restrict__ f2,
    const float* __restrict__ gate,
    float* __restrict__ smx0, float* __restrict__ sav0,
    float* __restrict__ smx1, float* __restrict__ sav1,
    float* __restrict__ smx2, float* __restrict__ sav2)
{
  const int lane = threadIdx.x & 63;
  const int wid = (blockIdx.x * blockDim.x + threadIdx.x) >> 6;
  const int nw = (gridDim.x * blockDim.x) >> 6;
  const int total = NB * 8400;
  for (int t = wid; t < total; t += nw) {
    const int b = t / 8400, p = t % 8400;
    const unsigned short* f; float* smx; float* sav; int s, pp, HW;
    if (p < 6400)      { s = 0; pp = p;        HW = 6400; f = f0; smx = smx0; sav = sav0; }
    else if (p < 8000) { s = 1; pp = p - 6400; HW = 1600; f = f1; smx = smx1; sav = sav1; }
    else               { s = 2; pp = p - 8000; HW = 400;  f = f2; smx = smx2; sav = sav2; }
    const unsigned u = ((const unsigned*)(f + ((size_t)b * HW + pp) * EMB))[lane];
    const float v0 = __uint_as_float(u << 16);
    const float v1 = __uint_as_float(u & 0xFFFF0000u);
    const int gb = (s * NB + b) * EMB + 2 * lane;
    const float y0 = gate[gb] * v0, y1 = gate[gb + 1] * v1;
    float m = fmaxf(y0, y1), sm = y0 + y1;
#pragma unroll
    for (int off = 1; off < 64; off <<= 1) { m = fmaxf(m, __shfl_xor(m, off, 64)); sm += __shfl_xor(sm, off, 64); }
    if (lane == 0) { smx[b * HW + pp] = m; sav[b * HW + pp] = sm * (1.f / EMB); }
  }
}

// ---------------- Kernel 4: 7x7 SAM conv at gathered pixels + final emb ----------------
__global__ __launch_bounds__(256) void gather_kernel(
    const int* __restrict__ reid_idx,
    const unsigned short* __restrict__ f0, const unsigned short* __restrict__ f1, const unsigned short* __restrict__ f2,
    const float* __restrict__ gate,
    const float* __restrict__ smx0, const float* __restrict__ sav0,
    const float* __restrict__ smx1, const float* __restrict__ sav1,
    const float* __restrict__ smx2, const float* __restrict__ sav2,
    const float* __restrict__ sw0, const float* __restrict__ sw1, const float* __restrict__ sw2,
    float* __restrict__ emb)
{
  const int lane = threadIdx.x & 63;
  const int wid = (blockIdx.x * blockDim.x + threadIdx.x) >> 6;
  if (wid >= NB * 100) return;
  const int b = wid / 100, k = wid % 100;
  const int idx = reid_idx[b * 100 + k];
  const unsigned short* f; const float* smx; const float* sav; const float* sw;
  int s, pp, W, H, HW;
  if (idx < 6400)      { s = 0; pp = idx;        W = 80; H = 80; HW = 6400; f = f0; smx = smx0; sav = sav0; sw = sw0; }
  else if (idx < 8000) { s = 1; pp = idx - 6400; W = 40; H = 40; HW = 1600; f = f1; smx = smx1; sav = sav1; sw = sw1; }
  else                 { s = 2; pp = idx - 8000; W = 20; H = 20; HW = 400;  f = f2; smx = smx2; sav = sav2; sw = sw2; }
  const int y = pp / W, xx0 = pp % W;
  float c = 0.f;
  if (lane < 49) {
    const int dy = lane / 7 - 3, dx = lane % 7 - 3;
    const int yy = y + dy, xx = xx0 + dx;
    if (yy >= 0 && yy < H && xx >= 0 && xx < W) {
      const int qq = b * HW + yy * W + xx;
      c = smx[qq] * sw[lane] + sav[qq] * sw[49 + lane];  // channel0=smx, channel1=sav
    }
  }
#pragma unroll
  for (int off = 1; off < 64; off <<= 1) c += __shfl_xor(c, off, 64);
  const float sig = 1.f / (1.f + __expf(-c));
  const unsigned u = ((const unsigned*)(f + ((size_t)b * HW + pp) * EMB))[lane];
  const float v0 = __uint_as_float(u << 16);
  const float v1 = __uint_as_float(u & 0xFFFF0000u);
  const int gb = (s * NB + b) * EMB + 2 * lane;
  const float o0 = v0 * (1.f + sig * gate[gb]);
  const float o1 = v1 * (1.f + sig * gate[gb + 1]);
  *(float2*)(emb + ((size_t)(b * 100 + k)) * EMB + 2 * lane) = make_float2(o0, o1);
}

// ---------------- Kernel 5: yolo passthrough copy (replaces SDMA memcpy) ----------------
__global__ __launch_bounds__(256) void ycopy_kernel(
    const float4* __restrict__ src, float4* __restrict__ dst, int n)
{
  const int i = blockIdx.x * 256 + threadIdx.x;
  if (i < n) dst[i] = src[i];
}

extern "C" void kernel_launch(void* const* d_in, const int* in_sizes, int n_in,
                              void* d_out, int out_size, void* d_ws, size_t ws_size,
                              hipStream_t stream)
{
  const float* xin0 = (const float*)d_in[0];
  const float* xin1 = (const float*)d_in[1];
  const float* xin2 = (const float*)d_in[2];
  const float* yolo = (const float*)d_in[3];
  const int*   reid = (const int*)d_in[4];
  const float* nw0 = (const float*)d_in[5];  const float* nb0 = (const float*)d_in[6];
  const float* nw1 = (const float*)d_in[7];  const float* nb1 = (const float*)d_in[8];
  const float* nw2 = (const float*)d_in[9];  const float* nb2 = (const float*)d_in[10];
  const float* c0w1 = (const float*)d_in[11]; const float* c0b1 = (const float*)d_in[12];
  const float* c0w2 = (const float*)d_in[13]; const float* c0b2 = (const float*)d_in[14];
  const float* c0sw = (const float*)d_in[15];
  const float* c1w1 = (const float*)d_in[16]; const float* c1b1 = (const float*)d_in[17];
  const float* c1w2 = (const float*)d_in[18]; const float* c1b2 = (const float*)d_in[19];
  const float* c1sw = (const float*)d_in[20];
  const float* c2w1 = (const float*)d_in[21]; const float* c2b1 = (const float*)d_in[22];
  const float* c2w2 = (const float*)d_in[23]; const float* c2b2 = (const float*)d_in[24];
  const float* c2sw = (const float*)d_in[25];

  char* ws = (char*)d_ws;
  size_t off = 0;
  auto alloc = [&](size_t bytes) -> void* {
    void* p = ws + off; off += (bytes + 255) & ~(size_t)255; return p;
  };
  unsigned short* f0 = (unsigned short*)alloc((size_t)NB * 6400 * EMB * 2);
  unsigned short* f1 = (unsigned short*)alloc((size_t)NB * 1600 * EMB * 2);
  unsigned short* f2 = (unsigned short*)alloc((size_t)NB * 400 * EMB * 2);
  unsigned* gmax = (unsigned*)alloc(3 * NB * EMB * 4);   // contiguous with gsum
  float* gsum = (float*)alloc(3 * NB * EMB * 4);
  float* gate = (float*)alloc(3 * NB * EMB * 4);
  float* smx0 = (float*)alloc((size_t)NB * 6400 * 4);
  float* sav0 = (float*)alloc((size_t)NB * 6400 * 4);
  float* smx1 = (float*)alloc((size_t)NB * 1600 * 4);
  float* sav1 = (float*)alloc((size_t)NB * 1600 * 4);
  float* smx2 = (float*)alloc((size_t)NB * 400 * 4);
  float* sav2 = (float*)alloc((size_t)NB * 400 * 4);
  unsigned short* wb0 = (unsigned short*)alloc(32768 * 2);
  unsigned short* wb1 = (unsigned short*)alloc(65536 * 2);
  unsigned short* wb2 = (unsigned short*)alloc(131072 * 2);

  wconv_kernel<<<dim3(896), dim3(256), 0, stream>>>(nw0, nw1, nw2, wb0, wb1, wb2, gmax);

  neck_kernel<<<dim3(2144), dim3(256), 0, stream>>>(
      xin0, xin1, xin2, wb0, wb1, wb2, nb0, nb1, nb2, f0, f1, f2, gmax, gsum);

  gate_kernel<<<dim3(NB, 3), dim3(128), 0, stream>>>(gmax, gsum, gate,
      c0w1, c0b1, c0w2, c0b2, c1w1, c1b1, c1w2, c1b2, c2w1, c2b1, c2w2, c2b2);

  smap_kernel<<<dim3(4200), dim3(256), 0, stream>>>(f0, f1, f2, gate, smx0, sav0, smx1, sav1, smx2, sav2);

  gather_kernel<<<dim3(800), dim3(256), 0, stream>>>(reid, f0, f1, f2, gate,
      smx0, sav0, smx1, sav1, smx2, sav2, c0sw, c1sw, c2sw,
      (float*)d_out + (size_t)NB * 8400 * 6);

  ycopy_kernel<<<dim3((NB * 8400 * 6 / 4 + 255) / 256), dim3(256), 0, stream>>>(
      (const float4*)yolo, (float4*)d_out, NB * 8400 * 6 / 4);
}